// Round 4
// baseline (660.886 us; speedup 1.0000x reference)
//
#include <hip/hip_runtime.h>
#include <hip/hip_bf16.h>
#include <stdint.h>

// Problem constants
#define N_S   16
#define C_IN  256
#define CMID  64
#define HH    96
#define WW    96
#define HW    9216     // 96*96
#define PL2   128      // PLANES/2
#define FSTR  152      // padded channel stride (bf16 elems) for f tile in LDS

// smalls[] fp32 layout (element offsets)
#define CB_OFF   0     // conv_b[64]
#define KW_OFF   64    // conv_kernel_w[25]
#define KB_OFF   96    // conv_kernel_b[25]
#define K2W_OFF  128   // conv_kernel2_w[9]
#define K2B_OFF  144   // conv_kernel2_b[9]
#define FB_OFF   160   // fuse_b[128]
#define AB_OFF   288   // adap_b[64]
#define ATB_OFF  352   // atrous_b[64]
#define SC_OFF   416   // conv_k_w, conv_k_b, conv_k2_w, conv_k2_b

// ---------- bf16 helpers (OCP bf16 = upper 16 bits of fp32) ----------
__device__ __forceinline__ float ldbf(const uint16_t* p) {
    return __uint_as_float(((uint32_t)(*p)) << 16);
}
__device__ __forceinline__ uint16_t f2bf(float f) {
    uint32_t u = __float_as_uint(f);
    u = (u + 0x7fffu + ((u >> 16) & 1u)) >> 16;   // RTNE
    return (uint16_t)u;
}
__device__ __forceinline__ void unpk2(uint32_t u, float& lo, float& hi) {
    lo = __uint_as_float(u << 16);
    hi = __uint_as_float(u & 0xffff0000u);
}

// ---------- P0: dtype probe. Counts bf16-exponent>=0xC0 in raw uint16 view ----------
// bf16-stored data (|v|<~6): count 0. fp32-stored data: low halves of words have
// pseudorandom exponents -> ~25% hits. flags[i]=1 means fp32.
__global__ __launch_bounds__(256) void k_probe(const uint16_t* __restrict__ xq,
                                               const uint16_t* __restrict__ wq,
                                               int* __restrict__ flags) {
    __shared__ int cnt[2];
    int t = threadIdx.x;
    if (t < 2) cnt[t] = 0;
    __syncthreads();
    int cx = 0, cw = 0;
    for (int k = 0; k < 64; ++k) {            // 16384 uint16 each (32 KB: safe for both dtypes)
        uint16_t vx = xq[k * 256 + t];
        uint16_t vw = wq[k * 256 + t];
        if (((vx >> 7) & 0xFF) >= 0xC0) cx++;
        if (((vw >> 7) & 0xFF) >= 0xC0) cw++;
    }
    atomicAdd(&cnt[0], cx);
    atomicAdd(&cnt[1], cw);
    __syncthreads();
    if (t == 0) { flags[0] = cnt[0] > 64; flags[1] = cnt[1] > 64; }
}

// ---------- P1: normalize weights: conv_w/fuse_w -> bf16, rest -> fp32 ----------
__global__ __launch_bounds__(256) void k_wnorm(
    const void* conv_w, const void* conv_b, const void* ckw, const void* ckb,
    const void* ck2w, const void* ck2b, const void* kernw, const void* kernb,
    const void* kern2w, const void* kern2b, const void* fuse_w, const void* fuse_b,
    const void* adap_b, const void* atrous_b,
    const int* __restrict__ flags,
    uint16_t* __restrict__ cw_bf, uint16_t* __restrict__ fw_bf,
    float* __restrict__ smalls) {
    int t = threadIdx.x;
    bool f32 = flags[1] != 0;
    for (int i = t; i < CMID * C_IN; i += 256)
        cw_bf[i] = f32 ? f2bf(((const float*)conv_w)[i]) : ((const uint16_t*)conv_w)[i];
    for (int i = t; i < PL2 * CMID; i += 256)
        fw_bf[i] = f32 ? f2bf(((const float*)fuse_w)[i]) : ((const uint16_t*)fuse_w)[i];
    if (t < 64) {
        smalls[CB_OFF + t]  = f32 ? ((const float*)conv_b)[t]   : ldbf((const uint16_t*)conv_b + t);
        smalls[AB_OFF + t]  = f32 ? ((const float*)adap_b)[t]   : ldbf((const uint16_t*)adap_b + t);
        smalls[ATB_OFF + t] = f32 ? ((const float*)atrous_b)[t] : ldbf((const uint16_t*)atrous_b + t);
    }
    if (t < 128)
        smalls[FB_OFF + t] = f32 ? ((const float*)fuse_b)[t] : ldbf((const uint16_t*)fuse_b + t);
    if (t < 25) {
        smalls[KW_OFF + t] = f32 ? ((const float*)kernw)[t] : ldbf((const uint16_t*)kernw + t);
        smalls[KB_OFF + t] = f32 ? ((const float*)kernb)[t] : ldbf((const uint16_t*)kernb + t);
    }
    if (t < 9) {
        smalls[K2W_OFF + t] = f32 ? ((const float*)kern2w)[t] : ldbf((const uint16_t*)kern2w + t);
        smalls[K2B_OFF + t] = f32 ? ((const float*)kern2b)[t] : ldbf((const uint16_t*)kern2b + t);
    }
    if (t == 0) {
        smalls[SC_OFF + 0] = f32 ? ((const float*)ckw)[0]  : ldbf((const uint16_t*)ckw);
        smalls[SC_OFF + 1] = f32 ? ((const float*)ckb)[0]  : ldbf((const uint16_t*)ckb);
        smalls[SC_OFF + 2] = f32 ? ((const float*)ck2w)[0] : ldbf((const uint16_t*)ck2w);
        smalls[SC_OFF + 3] = f32 ? ((const float*)ck2b)[0] : ldbf((const uint16_t*)ck2b);
    }
}

// ---------- K0: per-(n,c) channel sums over H*W (x dtype-branched) ----------
__global__ __launch_bounds__(256) void k_sums(const void* __restrict__ xv,
                                              const int* __restrict__ flags,
                                              float* __restrict__ sums) {
    int b = blockIdx.x;                       // b = n*256 + c, 4096 blocks
    int t = threadIdx.x;
    float s = 0.f;
    if (flags[0]) {                           // fp32 x
        const float4* xp = (const float4*)((const float*)xv + (size_t)b * HW);
#pragma unroll
        for (int k = 0; k < 9; ++k) {
            float4 v = xp[k * 256 + t];
            s += (v.x + v.y) + (v.z + v.w);
        }
    } else {                                  // bf16 x
        const uint2* xp = (const uint2*)((const uint16_t*)xv + (size_t)b * HW);
#pragma unroll
        for (int k = 0; k < 9; ++k) {
            uint2 v = xp[k * 256 + t];
            float a0, a1, a2, a3;
            unpk2(v.x, a0, a1);
            unpk2(v.y, a2, a3);
            s += (a0 + a1) + (a2 + a3);
        }
    }
#pragma unroll
    for (int off = 32; off > 0; off >>= 1) s += __shfl_down(s, off, 64);
    __shared__ float red[4];
    if ((t & 63) == 0) red[t >> 6] = s;
    __syncthreads();
    if (t == 0) sums[b] = red[0] + red[1] + red[2] + red[3];
}

// ---------- K1: tiny — g, then dynamic depthwise weights (fp32 to ws) ----------
__global__ __launch_bounds__(256) void k_weights(
    const float* __restrict__ sums, const uint16_t* __restrict__ cw_bf,
    const float* __restrict__ smalls,
    float* __restrict__ w_dyn, float* __restrict__ w_atr) {
    int g = blockIdx.x * 256 + threadIdx.x;
    if (g >= N_S * CMID) return;
    int n = g >> 6, cm = g & 63;
    const float inv = 1.0f / (float)HW;
    const uint16_t* wr = cw_bf + cm * C_IN;
    const float* sr = sums + n * C_IN;
    float acc = 0.f;
#pragma unroll 8
    for (int c = 0; c < C_IN; ++c)
        acc = fmaf(ldbf(wr + c), sr[c] * inv, acc);
    acc += smalls[CB_OFF + cm];
    float gv = fmaxf(acc, 0.f);
    float ckw = smalls[SC_OFF + 0], ckb = smalls[SC_OFF + 1];
    float ck2w = smalls[SC_OFF + 2], ck2b = smalls[SC_OFF + 3];
    float* o1 = w_dyn + (size_t)g * 25;
#pragma unroll
    for (int k = 0; k < 25; ++k)
        o1[k] = fmaf(ckw, fmaf(gv, smalls[KW_OFF + k], smalls[KB_OFF + k]), ckb);
    float* o2 = w_atr + (size_t)g * 9;
#pragma unroll
    for (int k = 0; k < 9; ++k)
        o2[k] = fmaf(ck2w, fmaf(gv, smalls[K2W_OFF + k], smalls[K2B_OFF + k]), ck2b);
}

// ---------- K2: f = relu(1x1 conv) -> f bf16; x dtype-branched staging ----------
// grid: 16 samples * 72 tiles of 128 px; block 256 thr; thread: 8 outs x 4 px
__global__ __launch_bounds__(256) void k_conv1x1(
    const void* __restrict__ xv, const int* __restrict__ flags,
    const uint16_t* __restrict__ cw_bf, const float* __restrict__ smalls,
    uint16_t* __restrict__ fout) {
    __shared__ uint16_t w_lds[C_IN * CMID];   // [c][o], 32 KB
    __shared__ uint16_t x_lds[16 * 128];      // 4 KB, [c][px] bf16
    int t = threadIdx.x;
    int b = blockIdx.x;
    int n = b / 72, tile = b % 72;
    int pxb = tile * 128;
    bool xf32 = flags[0] != 0;

    // stage W transposed: w_lds[c*64+o] = cw_bf[o*256+c]
    for (int k = 0; k < 64; ++k) {
        int lin = k * 256 + t;
        int o = lin & 63, c = lin >> 6;
        w_lds[c * 64 + o] = cw_bf[o * C_IN + c];
    }

    float acc[8][4];
#pragma unroll
    for (int i = 0; i < 8; ++i)
#pragma unroll
        for (int j = 0; j < 4; ++j) acc[i][j] = 0.f;

    size_t xoff = (size_t)n * C_IN * HW + pxb;
    int px0 = (t & 31) << 2;      // 0..124
    int o0  = (t >> 5) << 3;      // 0..56

    for (int cc = 0; cc < C_IN; cc += 16) {
        __syncthreads();
        if (xf32) {
            const float* xbase = (const float*)xv + xoff;
#pragma unroll
            for (int k = 0; k < 2; ++k) {
                int q = k * 256 + t;
                int cl = q >> 5, p4 = (q & 31) << 2;
                float4 v = *(const float4*)(xbase + (size_t)(cc + cl) * HW + p4);
                uint32_t lo = (uint32_t)f2bf(v.x) | ((uint32_t)f2bf(v.y) << 16);
                uint32_t hi = (uint32_t)f2bf(v.z) | ((uint32_t)f2bf(v.w) << 16);
                *(uint2*)(x_lds + cl * 128 + p4) = make_uint2(lo, hi);
            }
        } else {
            const uint16_t* xbase = (const uint16_t*)xv + xoff;
#pragma unroll
            for (int k = 0; k < 2; ++k) {
                int q = k * 256 + t;
                int cl = q >> 5, p4 = (q & 31) << 2;
                *(uint2*)(x_lds + cl * 128 + p4) =
                    *(const uint2*)(xbase + (size_t)(cc + cl) * HW + p4);
            }
        }
        __syncthreads();
#pragma unroll
        for (int ci = 0; ci < 16; ++ci) {
            uint4 wv = *(const uint4*)(w_lds + (cc + ci) * 64 + o0);
            float wf[8];
            unpk2(wv.x, wf[0], wf[1]);
            unpk2(wv.y, wf[2], wf[3]);
            unpk2(wv.z, wf[4], wf[5]);
            unpk2(wv.w, wf[6], wf[7]);
            uint2 xvv = *(const uint2*)(x_lds + ci * 128 + px0);
            float xf[4];
            unpk2(xvv.x, xf[0], xf[1]);
            unpk2(xvv.y, xf[2], xf[3]);
#pragma unroll
            for (int o = 0; o < 8; ++o)
#pragma unroll
                for (int p = 0; p < 4; ++p)
                    acc[o][p] = fmaf(wf[o], xf[p], acc[o][p]);
        }
    }

    uint16_t* fb = fout + (size_t)(n * CMID + o0) * HW + pxb + px0;
#pragma unroll
    for (int oo = 0; oo < 8; ++oo) {
        float bv = smalls[CB_OFF + o0 + oo];
        float v0 = fmaxf(acc[oo][0] + bv, 0.f);
        float v1 = fmaxf(acc[oo][1] + bv, 0.f);
        float v2 = fmaxf(acc[oo][2] + bv, 0.f);
        float v3 = fmaxf(acc[oo][3] + bv, 0.f);
        uint32_t lo = (uint32_t)f2bf(v0) | ((uint32_t)f2bf(v1) << 16);
        uint32_t hi = (uint32_t)f2bf(v2) | ((uint32_t)f2bf(v3) << 16);
        *(uint2*)(fb + (size_t)oo * HW) = make_uint2(lo, hi);
    }
}

// ---------- K3: fused dynamic depthwise (5x5 + atrous 3x3) + fuse GEMM ----------
// grid: 16 samples * 144 tiles of 8x8 px; block 256 thr; OUTPUT FP32
__global__ __launch_bounds__(256) void k_dwfuse(
    const uint16_t* __restrict__ f,
    const float* __restrict__ w_dyn, const float* __restrict__ w_atr,
    const uint16_t* __restrict__ fw_bf, const float* __restrict__ smalls,
    float* __restrict__ out) {
    __shared__ uint16_t f_lds[CMID * FSTR];   // 19456 B: 64 ch x 12x12 halo tile
    __shared__ uint16_t d5_lds[CMID * 64];    // 8 KB
    __shared__ uint16_t dA_lds[CMID * 64];    // 8 KB
    __shared__ uint16_t fw_lds[CMID * PL2];   // 16 KB, [c][o]

    int t = threadIdx.x;
    int b = blockIdx.x;
    int n = b / 144, tile = b % 144;
    int y0 = (tile / 12) * 8, x0 = (tile % 12) * 8;

    // stage fuse_w transposed
#pragma unroll
    for (int k = 0; k < 32; ++k) {
        int lin = k * 256 + t;
        int o = lin & 127, c = lin >> 7;
        fw_lds[c * PL2 + o] = fw_bf[o * CMID + c];
    }
    // stage f tile (12x12 with halo 2, zero-padded at borders)
    const uint16_t* fbase = f + (size_t)n * CMID * HW;
    for (int k = 0; k < 36; ++k) {
        int lin = k * 256 + t;                // 0..9215
        int c = lin / 144;
        int r = lin - c * 144;
        int yy = r / 12, xx = r - yy * 12;
        int y = y0 - 2 + yy, xg = x0 - 2 + xx;
        uint16_t v = 0;
        if (y >= 0 && y < HH && xg >= 0 && xg < WW)
            v = fbase[(size_t)c * HW + y * WW + xg];
        f_lds[c * FSTR + yy * 12 + xx] = v;
    }
    __syncthreads();

    // ---- phase 2: depthwise, one channel x 4x4 patch per thread ----
    {
        int c = t >> 2, q = t & 3;
        int qy = (q >> 1) << 2, qx = (q & 1) << 2;

        float w5[25], w9[9];
        const float* wp = w_dyn + (size_t)(n * CMID + c) * 25;
#pragma unroll
        for (int k = 0; k < 25; ++k) w5[k] = wp[k];
        const float* wa = w_atr + (size_t)(n * CMID + c) * 9;
#pragma unroll
        for (int k = 0; k < 9; ++k) w9[k] = wa[k];

        float p[8][8];
#pragma unroll
        for (int r = 0; r < 8; ++r) {
            const uint16_t* rp = f_lds + c * FSTR + (qy + r) * 12 + qx;
            uint2 a  = *(const uint2*)rp;
            uint2 b2 = *(const uint2*)(rp + 4);
            unpk2(a.x,  p[r][0], p[r][1]);
            unpk2(a.y,  p[r][2], p[r][3]);
            unpk2(b2.x, p[r][4], p[r][5]);
            unpk2(b2.y, p[r][6], p[r][7]);
        }

        float b5v = smalls[AB_OFF + c], bAv = smalls[ATB_OFF + c];
        float a5[4][4], aA[4][4];
#pragma unroll
        for (int i = 0; i < 4; ++i)
#pragma unroll
            for (int j = 0; j < 4; ++j) { a5[i][j] = b5v; aA[i][j] = bAv; }

#pragma unroll
        for (int i = 0; i < 5; ++i)
#pragma unroll
            for (int j = 0; j < 5; ++j) {
                float wv = w5[i * 5 + j];
#pragma unroll
                for (int oy = 0; oy < 4; ++oy)
#pragma unroll
                    for (int ox = 0; ox < 4; ++ox)
                        a5[oy][ox] = fmaf(wv, p[oy + i][ox + j], a5[oy][ox]);
            }
#pragma unroll
        for (int i = 0; i < 3; ++i)
#pragma unroll
            for (int j = 0; j < 3; ++j) {
                float wv = w9[i * 3 + j];
#pragma unroll
                for (int oy = 0; oy < 4; ++oy)
#pragma unroll
                    for (int ox = 0; ox < 4; ++ox)
                        aA[oy][ox] = fmaf(wv, p[oy + 2 * i][ox + 2 * j], aA[oy][ox]);
            }

#pragma unroll
        for (int oy = 0; oy < 4; ++oy) {
            uint32_t l5 = (uint32_t)f2bf(a5[oy][0]) | ((uint32_t)f2bf(a5[oy][1]) << 16);
            uint32_t h5 = (uint32_t)f2bf(a5[oy][2]) | ((uint32_t)f2bf(a5[oy][3]) << 16);
            *(uint2*)(d5_lds + c * 64 + (qy + oy) * 8 + qx) = make_uint2(l5, h5);
            uint32_t lA = (uint32_t)f2bf(aA[oy][0]) | ((uint32_t)f2bf(aA[oy][1]) << 16);
            uint32_t hA = (uint32_t)f2bf(aA[oy][2]) | ((uint32_t)f2bf(aA[oy][3]) << 16);
            *(uint2*)(dA_lds + c * 64 + (qy + oy) * 8 + qx) = make_uint2(lA, hA);
        }
    }
    __syncthreads();

    // ---- phase 3: fuse GEMM, thread = 8 outs x 4 px x 2 branches; fp32 out ----
    {
        int pxg = t & 15, og = t >> 4;
        int p0 = pxg << 2;            // 0..60
        int o8 = og << 3;             // 0..120
        float acc1[8][4], acc2[8][4];
#pragma unroll
        for (int oo = 0; oo < 8; ++oo) {
            float bo = smalls[FB_OFF + o8 + oo];
#pragma unroll
            for (int pp = 0; pp < 4; ++pp) { acc1[oo][pp] = bo; acc2[oo][pp] = bo; }
        }
#pragma unroll 4
        for (int c = 0; c < CMID; ++c) {
            uint4 wv = *(const uint4*)(fw_lds + c * PL2 + o8);
            float wf[8];
            unpk2(wv.x, wf[0], wf[1]);
            unpk2(wv.y, wf[2], wf[3]);
            unpk2(wv.z, wf[4], wf[5]);
            unpk2(wv.w, wf[6], wf[7]);
            uint2 u5 = *(const uint2*)(d5_lds + c * 64 + p0);
            uint2 uA = *(const uint2*)(dA_lds + c * 64 + p0);
            float d5f[4], dAf[4];
            unpk2(u5.x, d5f[0], d5f[1]);
            unpk2(u5.y, d5f[2], d5f[3]);
            unpk2(uA.x, dAf[0], dAf[1]);
            unpk2(uA.y, dAf[2], dAf[3]);
#pragma unroll
            for (int oo = 0; oo < 8; ++oo)
#pragma unroll
                for (int pp = 0; pp < 4; ++pp) {
                    acc1[oo][pp] = fmaf(wf[oo], d5f[pp], acc1[oo][pp]);
                    acc2[oo][pp] = fmaf(wf[oo], dAf[pp], acc2[oo][pp]);
                }
        }
        int py = p0 >> 3, pxx = p0 & 7;
        int yg = y0 + py, xg = x0 + pxx;
        size_t base = ((size_t)n * 256) * HW + (size_t)yg * WW + xg;
#pragma unroll
        for (int oo = 0; oo < 8; ++oo) {
            *(float4*)(out + base + (size_t)(o8 + oo) * HW) =
                make_float4(acc1[oo][0], acc1[oo][1], acc1[oo][2], acc1[oo][3]);
            *(float4*)(out + base + (size_t)(128 + o8 + oo) * HW) =
                make_float4(acc2[oo][0], acc2[oo][1], acc2[oo][2], acc2[oo][3]);
        }
    }
}

extern "C" void kernel_launch(void* const* d_in, const int* in_sizes, int n_in,
                              void* d_out, int out_size, void* d_ws, size_t ws_size,
                              hipStream_t stream) {
    float* out = (float*)d_out;                              // fp32 output

    char* ws = (char*)d_ws;
    int*      flags = (int*)ws;                              // 256 B reserved
    uint16_t* cw_bf = (uint16_t*)(ws + 256);                 // 32768 B
    uint16_t* fw_bf = (uint16_t*)(ws + 33024);               // 16384 B
    float*    smalls = (float*)(ws + 49408);                 // 2048 B (pad to 65536)
    float*    sums  = (float*)(ws + 65536);                  // 16384 B
    float*    w_dyn = (float*)(ws + 81920);                  // 102400 B
    float*    w_atr = (float*)(ws + 184320);                 // 36864 B
    uint16_t* f     = (uint16_t*)(ws + 221184);              // 18.9 MB bf16

    k_probe<<<dim3(1), dim3(256), 0, stream>>>(
        (const uint16_t*)d_in[0], (const uint16_t*)d_in[1], flags);
    k_wnorm<<<dim3(1), dim3(256), 0, stream>>>(
        d_in[1], d_in[2], d_in[3], d_in[4], d_in[5], d_in[6], d_in[7], d_in[8],
        d_in[9], d_in[10], d_in[11], d_in[12], d_in[13], d_in[14],
        flags, cw_bf, fw_bf, smalls);
    k_sums<<<dim3(N_S * C_IN), dim3(256), 0, stream>>>(d_in[0], flags, sums);
    k_weights<<<dim3(4), dim3(256), 0, stream>>>(sums, cw_bf, smalls, w_dyn, w_atr);
    k_conv1x1<<<dim3(N_S * 72), dim3(256), 0, stream>>>(d_in[0], flags, cw_bf, smalls, f);
    k_dwfuse<<<dim3(N_S * 144), dim3(256), 0, stream>>>(
        f, w_dyn, w_atr, fw_bf, smalls, out);
}

// Round 5
// 462.738 us; speedup vs baseline: 1.4282x; 1.4282x over previous
//
#include <hip/hip_runtime.h>
#include <hip/hip_bf16.h>
#include <stdint.h>

// Problem constants
#define N_S   16
#define C_IN  256
#define CMID  64
#define HH    96
#define WW    96
#define HW    9216     // 96*96
#define PL2   128      // PLANES/2

// smalls[] fp32 layout (element offsets)
#define CB_OFF   0     // conv_b[64]
#define KW_OFF   64    // conv_kernel_w[25]
#define KB_OFF   96    // conv_kernel_b[25]
#define K2W_OFF  128   // conv_kernel2_w[9]
#define K2B_OFF  144   // conv_kernel2_b[9]
#define FB_OFF   160   // fuse_b[128]
#define AB_OFF   288   // adap_b[64]
#define ATB_OFF  352   // atrous_b[64]
#define SC_OFF   416   // conv_k_w, conv_k_b, conv_k2_w, conv_k2_b

typedef __attribute__((ext_vector_type(8))) short short8;   // 8 bf16 = 4 VGPRs
typedef __attribute__((ext_vector_type(4))) float floatx4;  // MFMA acc

// ---------- bf16 helpers (OCP bf16 = upper 16 bits of fp32) ----------
__device__ __forceinline__ float ldbf(const uint16_t* p) {
    return __uint_as_float(((uint32_t)(*p)) << 16);
}
__device__ __forceinline__ uint16_t f2bf(float f) {
    uint32_t u = __float_as_uint(f);
    u = (u + 0x7fffu + ((u >> 16) & 1u)) >> 16;   // RTNE
    return (uint16_t)u;
}

// ---------- P0: dtype probe (flags[i]=1 means fp32-stored) ----------
__global__ __launch_bounds__(256) void k_probe(const uint16_t* __restrict__ xq,
                                               const uint16_t* __restrict__ wq,
                                               int* __restrict__ flags) {
    __shared__ int cnt[2];
    int t = threadIdx.x;
    if (t < 2) cnt[t] = 0;
    __syncthreads();
    int cx = 0, cw = 0;
    for (int k = 0; k < 64; ++k) {
        uint16_t vx = xq[k * 256 + t];
        uint16_t vw = wq[k * 256 + t];
        if (((vx >> 7) & 0xFF) >= 0xC0) cx++;
        if (((vw >> 7) & 0xFF) >= 0xC0) cw++;
    }
    atomicAdd(&cnt[0], cx);
    atomicAdd(&cnt[1], cw);
    __syncthreads();
    if (t == 0) { flags[0] = cnt[0] > 64; flags[1] = cnt[1] > 64; }
}

// ---------- P1: normalize weights: conv_w/fuse_w -> bf16, rest -> fp32 ----------
__global__ __launch_bounds__(256) void k_wnorm(
    const void* conv_w, const void* conv_b, const void* ckw, const void* ckb,
    const void* ck2w, const void* ck2b, const void* kernw, const void* kernb,
    const void* kern2w, const void* kern2b, const void* fuse_w, const void* fuse_b,
    const void* adap_b, const void* atrous_b,
    const int* __restrict__ flags,
    uint16_t* __restrict__ cw_bf, uint16_t* __restrict__ fw_bf,
    float* __restrict__ smalls) {
    int t = threadIdx.x;
    bool f32 = flags[1] != 0;
    for (int i = t; i < CMID * C_IN; i += 256)
        cw_bf[i] = f32 ? f2bf(((const float*)conv_w)[i]) : ((const uint16_t*)conv_w)[i];
    for (int i = t; i < PL2 * CMID; i += 256)
        fw_bf[i] = f32 ? f2bf(((const float*)fuse_w)[i]) : ((const uint16_t*)fuse_w)[i];
    if (t < 64) {
        smalls[CB_OFF + t]  = f32 ? ((const float*)conv_b)[t]   : ldbf((const uint16_t*)conv_b + t);
        smalls[AB_OFF + t]  = f32 ? ((const float*)adap_b)[t]   : ldbf((const uint16_t*)adap_b + t);
        smalls[ATB_OFF + t] = f32 ? ((const float*)atrous_b)[t] : ldbf((const uint16_t*)atrous_b + t);
    }
    if (t < 128)
        smalls[FB_OFF + t] = f32 ? ((const float*)fuse_b)[t] : ldbf((const uint16_t*)fuse_b + t);
    if (t < 25) {
        smalls[KW_OFF + t] = f32 ? ((const float*)kernw)[t] : ldbf((const uint16_t*)kernw + t);
        smalls[KB_OFF + t] = f32 ? ((const float*)kernb)[t] : ldbf((const uint16_t*)kernb + t);
    }
    if (t < 9) {
        smalls[K2W_OFF + t] = f32 ? ((const float*)kern2w)[t] : ldbf((const uint16_t*)kern2w + t);
        smalls[K2B_OFF + t] = f32 ? ((const float*)kern2b)[t] : ldbf((const uint16_t*)kern2b + t);
    }
    if (t == 0) {
        smalls[SC_OFF + 0] = f32 ? ((const float*)ckw)[0]  : ldbf((const uint16_t*)ckw);
        smalls[SC_OFF + 1] = f32 ? ((const float*)ckb)[0]  : ldbf((const uint16_t*)ckb);
        smalls[SC_OFF + 2] = f32 ? ((const float*)ck2w)[0] : ldbf((const uint16_t*)ck2w);
        smalls[SC_OFF + 3] = f32 ? ((const float*)ck2b)[0] : ldbf((const uint16_t*)ck2b);
    }
}

// ---------- K0: per-(n,c) channel sums over H*W (x dtype-branched) ----------
__global__ __launch_bounds__(256) void k_sums(const void* __restrict__ xv,
                                              const int* __restrict__ flags,
                                              float* __restrict__ sums) {
    int b = blockIdx.x;                       // b = n*256 + c
    int t = threadIdx.x;
    float s = 0.f;
    if (flags[0]) {                           // fp32 x
        const float4* xp = (const float4*)((const float*)xv + (size_t)b * HW);
#pragma unroll
        for (int k = 0; k < 9; ++k) {
            float4 v = xp[k * 256 + t];
            s += (v.x + v.y) + (v.z + v.w);
        }
    } else {                                  // bf16 x
        const uint2* xp = (const uint2*)((const uint16_t*)xv + (size_t)b * HW);
#pragma unroll
        for (int k = 0; k < 9; ++k) {
            uint2 v = xp[k * 256 + t];
            s += (__uint_as_float(v.x << 16) + __uint_as_float(v.x & 0xffff0000u))
               + (__uint_as_float(v.y << 16) + __uint_as_float(v.y & 0xffff0000u));
        }
    }
#pragma unroll
    for (int off = 32; off > 0; off >>= 1) s += __shfl_down(s, off, 64);
    __shared__ float red[4];
    if ((t & 63) == 0) red[t >> 6] = s;
    __syncthreads();
    if (t == 0) sums[b] = red[0] + red[1] + red[2] + red[3];
}

// ---------- K1: tiny — g, then dynamic depthwise weights (fp32 to ws) ----------
__global__ __launch_bounds__(256) void k_weights(
    const float* __restrict__ sums, const uint16_t* __restrict__ cw_bf,
    const float* __restrict__ smalls,
    float* __restrict__ w_dyn, float* __restrict__ w_atr) {
    int g = blockIdx.x * 256 + threadIdx.x;
    if (g >= N_S * CMID) return;
    int n = g >> 6, cm = g & 63;
    const float inv = 1.0f / (float)HW;
    const uint16_t* wr = cw_bf + cm * C_IN;
    const float* sr = sums + n * C_IN;
    float acc = 0.f;
#pragma unroll 8
    for (int c = 0; c < C_IN; ++c)
        acc = fmaf(ldbf(wr + c), sr[c] * inv, acc);
    acc += smalls[CB_OFF + cm];
    float gv = fmaxf(acc, 0.f);
    float ckw = smalls[SC_OFF + 0], ckb = smalls[SC_OFF + 1];
    float ck2w = smalls[SC_OFF + 2], ck2b = smalls[SC_OFF + 3];
    float* o1 = w_dyn + (size_t)g * 25;
#pragma unroll
    for (int k = 0; k < 25; ++k)
        o1[k] = fmaf(ckw, fmaf(gv, smalls[KW_OFF + k], smalls[KB_OFF + k]), ckb);
    float* o2 = w_atr + (size_t)g * 9;
#pragma unroll
    for (int k = 0; k < 9; ++k)
        o2[k] = fmaf(ck2w, fmaf(gv, smalls[K2W_OFF + k], smalls[K2B_OFF + k]), ck2b);
}

// ---------- K2: f = relu(1x1 conv) via MFMA; f stored [n][px][c] bf16 ----------
// grid: 16 * 72 tiles of 128 px; block 256 (4 waves); wave: M=64 x N=32px
__global__ __launch_bounds__(256) void k_conv1x1(
    const void* __restrict__ xv, const int* __restrict__ flags,
    const uint16_t* __restrict__ cw_bf, const float* __restrict__ smalls,
    uint16_t* __restrict__ fout) {
    __shared__ uint16_t w_lds[64 * 264];      // [o][c] pad 264 -> 33792 B
    __shared__ uint16_t x_lds[128 * 72];      // [px][c-chunk] pad 72 -> 18432 B
    int t = threadIdx.x;
    int b = blockIdx.x;
    int n = b / 72, pxb = (b % 72) * 128;
    bool xf32 = flags[0] != 0;

    // stage W: cw_bf[o][256] -> w_lds[o][264]
#pragma unroll
    for (int k = 0; k < 8; ++k) {
        int task = k * 256 + t;
        int o = task >> 5, c8 = (task & 31) * 8;
        *(uint4*)(w_lds + o * 264 + c8) = *(const uint4*)(cw_bf + o * 256 + c8);
    }

    int lane = t & 63, wid = t >> 6;
    int l16 = lane & 15, quad = lane >> 4;
    int nb = wid * 32;
    uint32_t* xl32 = (uint32_t*)x_lds;        // [px] stride 36 uints

    floatx4 acc[4][2];
#pragma unroll
    for (int i = 0; i < 4; ++i)
#pragma unroll
        for (int j = 0; j < 2; ++j) acc[i][j] = (floatx4){0.f, 0.f, 0.f, 0.f};

    for (int cc = 0; cc < 4; ++cc) {          // K chunks of 64 c
        __syncthreads();
        // stage+transpose 64c x 128px: pairs (c,c+1) packed per px
#pragma unroll
        for (int k = 0; k < 2; ++k) {
            int task = k * 256 + t;
            int pxg = task & 15, cp = task >> 4;      // cp 0..31
            int c = cc * 64 + cp * 2;
            int px0 = pxb + pxg * 8;
            uint16_t r0[8], r1[8];
            if (xf32) {
                const float* xb = (const float*)xv + ((size_t)n * C_IN + c) * HW + px0;
                float4 a0 = *(const float4*)xb, a1 = *(const float4*)(xb + 4);
                float4 b0 = *(const float4*)(xb + HW), b1 = *(const float4*)(xb + HW + 4);
                r0[0]=f2bf(a0.x); r0[1]=f2bf(a0.y); r0[2]=f2bf(a0.z); r0[3]=f2bf(a0.w);
                r0[4]=f2bf(a1.x); r0[5]=f2bf(a1.y); r0[6]=f2bf(a1.z); r0[7]=f2bf(a1.w);
                r1[0]=f2bf(b0.x); r1[1]=f2bf(b0.y); r1[2]=f2bf(b0.z); r1[3]=f2bf(b0.w);
                r1[4]=f2bf(b1.x); r1[5]=f2bf(b1.y); r1[6]=f2bf(b1.z); r1[7]=f2bf(b1.w);
            } else {
                const uint16_t* xb = (const uint16_t*)xv + ((size_t)n * C_IN + c) * HW + px0;
                uint4 v0 = *(const uint4*)xb;
                uint4 v1 = *(const uint4*)(xb + HW);
                r0[0]=(uint16_t)v0.x; r0[1]=(uint16_t)(v0.x>>16);
                r0[2]=(uint16_t)v0.y; r0[3]=(uint16_t)(v0.y>>16);
                r0[4]=(uint16_t)v0.z; r0[5]=(uint16_t)(v0.z>>16);
                r0[6]=(uint16_t)v0.w; r0[7]=(uint16_t)(v0.w>>16);
                r1[0]=(uint16_t)v1.x; r1[1]=(uint16_t)(v1.x>>16);
                r1[2]=(uint16_t)v1.y; r1[3]=(uint16_t)(v1.y>>16);
                r1[4]=(uint16_t)v1.z; r1[5]=(uint16_t)(v1.z>>16);
                r1[6]=(uint16_t)v1.w; r1[7]=(uint16_t)(v1.w>>16);
            }
#pragma unroll
            for (int j = 0; j < 8; ++j)
                xl32[(pxg * 8 + j) * 36 + cp] = (uint32_t)r0[j] | ((uint32_t)r1[j] << 16);
        }
        __syncthreads();
        // MFMA: A[m=o][k], B[k][n=px]; lane: m/n = l16, k = quad*8+j
#pragma unroll
        for (int ks = 0; ks < 2; ++ks) {
            int kw = cc * 64 + ks * 32 + quad * 8;
            int kx = ks * 32 + quad * 8;
            short8 a0 = *(const short8*)(w_lds + (l16)      * 264 + kw);
            short8 a1 = *(const short8*)(w_lds + (16 + l16) * 264 + kw);
            short8 a2 = *(const short8*)(w_lds + (32 + l16) * 264 + kw);
            short8 a3 = *(const short8*)(w_lds + (48 + l16) * 264 + kw);
#pragma unroll
            for (int nt = 0; nt < 2; ++nt) {
                short8 bv = *(const short8*)(x_lds + (nb + nt * 16 + l16) * 72 + kx);
                acc[0][nt] = __builtin_amdgcn_mfma_f32_16x16x32_bf16(a0, bv, acc[0][nt], 0, 0, 0);
                acc[1][nt] = __builtin_amdgcn_mfma_f32_16x16x32_bf16(a1, bv, acc[1][nt], 0, 0, 0);
                acc[2][nt] = __builtin_amdgcn_mfma_f32_16x16x32_bf16(a2, bv, acc[2][nt], 0, 0, 0);
                acc[3][nt] = __builtin_amdgcn_mfma_f32_16x16x32_bf16(a3, bv, acc[3][nt], 0, 0, 0);
            }
        }
    }

    // epilogue: D[col=px=l16][row=o=quad*4+reg]; bias+relu+bf16 -> x_lds [px][o]
    __syncthreads();
#pragma unroll
    for (int mt = 0; mt < 4; ++mt) {
        int o = mt * 16 + quad * 4;
        float b0 = smalls[CB_OFF + o],     b1 = smalls[CB_OFF + o + 1];
        float b2 = smalls[CB_OFF + o + 2], b3 = smalls[CB_OFF + o + 3];
#pragma unroll
        for (int nt = 0; nt < 2; ++nt) {
            int pxl = nb + nt * 16 + l16;
            float v0 = fmaxf(acc[mt][nt][0] + b0, 0.f);
            float v1 = fmaxf(acc[mt][nt][1] + b1, 0.f);
            float v2 = fmaxf(acc[mt][nt][2] + b2, 0.f);
            float v3 = fmaxf(acc[mt][nt][3] + b3, 0.f);
            uint32_t lo = (uint32_t)f2bf(v0) | ((uint32_t)f2bf(v1) << 16);
            uint32_t hi = (uint32_t)f2bf(v2) | ((uint32_t)f2bf(v3) << 16);
            *(uint2*)(x_lds + pxl * 72 + o) = make_uint2(lo, hi);
        }
    }
    __syncthreads();
    // coalesced copy-out: f[n][pxb+pxl][o]
#pragma unroll
    for (int k = 0; k < 4; ++k) {
        int task = k * 256 + t;
        int o8 = (task & 7) * 8, pxl = task >> 3;
        *(uint4*)(fout + ((size_t)n * HW + pxb + pxl) * 64 + o8) =
            *(const uint4*)(x_lds + pxl * 72 + o8);
    }
}

// ---------- K3: dynamic depthwise (5x5 + atrous 3x3) + MFMA fuse GEMM ----------
// grid 16*144 tiles of 8x8 px; block 256; f input layout [n][px][c]
__global__ __launch_bounds__(256) void k_dwfuse(
    const uint16_t* __restrict__ f,
    const float* __restrict__ w_dyn, const float* __restrict__ w_atr,
    const uint16_t* __restrict__ fw_bf, const float* __restrict__ smalls,
    float* __restrict__ out) {
    __shared__ uint16_t f_lds[144 * 72];      // [pxl 12x12][c] pad 72 -> 20736 B
    __shared__ uint16_t d5_lds[64 * 72];      // [px 8x8][c]  -> 9216 B
    __shared__ uint16_t dA_lds[64 * 72];      // 9216 B
    __shared__ uint16_t fw_lds[128 * 72];     // [o][c] pad 72 -> 18432 B

    int t = threadIdx.x;
    int b = blockIdx.x;
    int n = b / 144, tile = b % 144;
    int y0 = (tile / 12) * 8, x0 = (tile % 12) * 8;

    // stage fuse_w [o][64] -> fw_lds[o][72]
#pragma unroll
    for (int k = 0; k < 4; ++k) {
        int task = k * 256 + t;
        int o = task >> 3, c8 = (task & 7) * 8;
        *(uint4*)(fw_lds + o * 72 + c8) = *(const uint4*)(fw_bf + o * 64 + c8);
    }
    // stage f halo 12x12 x 64c (coalesced, zero-padded)
    const uint16_t* fbase = f + (size_t)n * HW * 64;
    for (int k = 0; k < 5; ++k) {
        int task = k * 256 + t;
        if (task < 1152) {
            int row = task >> 3, c8 = (task & 7) * 8;
            int yy = row / 12, xx = row - yy * 12;
            int y = y0 - 2 + yy, xg = x0 - 2 + xx;
            uint4 v = make_uint4(0u, 0u, 0u, 0u);
            if (y >= 0 && y < HH && xg >= 0 && xg < WW)
                v = *(const uint4*)(fbase + ((size_t)y * WW + xg) * 64 + c8);
            *(uint4*)(f_lds + row * 72 + c8) = v;
        }
    }
    __syncthreads();

    // ---- depthwise: one channel x 4x4 patch per thread ----
    {
        int c = t >> 2, q = t & 3;
        int qy = (q >> 1) << 2, qx = (q & 1) << 2;

        float w5[25], w9[9];
        const float* wp = w_dyn + (size_t)(n * CMID + c) * 25;
#pragma unroll
        for (int k = 0; k < 25; ++k) w5[k] = wp[k];
        const float* wa = w_atr + (size_t)(n * CMID + c) * 9;
#pragma unroll
        for (int k = 0; k < 9; ++k) w9[k] = wa[k];

        float p[8][8];
#pragma unroll
        for (int r = 0; r < 8; ++r)
#pragma unroll
            for (int cl = 0; cl < 8; ++cl)
                p[r][cl] = ldbf(f_lds + ((qy + r) * 12 + qx + cl) * 72 + c);

        float b5v = smalls[AB_OFF + c], bAv = smalls[ATB_OFF + c];
        float a5[4][4], aA[4][4];
#pragma unroll
        for (int i = 0; i < 4; ++i)
#pragma unroll
            for (int j = 0; j < 4; ++j) { a5[i][j] = b5v; aA[i][j] = bAv; }

#pragma unroll
        for (int i = 0; i < 5; ++i)
#pragma unroll
            for (int j = 0; j < 5; ++j) {
                float wv = w5[i * 5 + j];
#pragma unroll
                for (int oy = 0; oy < 4; ++oy)
#pragma unroll
                    for (int ox = 0; ox < 4; ++ox)
                        a5[oy][ox] = fmaf(wv, p[oy + i][ox + j], a5[oy][ox]);
            }
#pragma unroll
        for (int i = 0; i < 3; ++i)
#pragma unroll
            for (int j = 0; j < 3; ++j) {
                float wv = w9[i * 3 + j];
#pragma unroll
                for (int oy = 0; oy < 4; ++oy)
#pragma unroll
                    for (int ox = 0; ox < 4; ++ox)
                        aA[oy][ox] = fmaf(wv, p[oy + 2 * i][ox + 2 * j], aA[oy][ox]);
            }

#pragma unroll
        for (int oy = 0; oy < 4; ++oy)
#pragma unroll
            for (int ox = 0; ox < 4; ++ox) {
                int pxo = (qy + oy) * 8 + qx + ox;
                d5_lds[pxo * 72 + c] = f2bf(a5[oy][ox]);
                dA_lds[pxo * 72 + c] = f2bf(aA[oy][ox]);
            }
    }
    __syncthreads();

    // ---- fuse GEMM via MFMA: wave = (branch, o-half); M=64 o x N=64 px, K=64 ----
    {
        int lane = t & 63, wid = t >> 6;
        int l16 = lane & 15, quad = lane >> 4;
        const uint16_t* dl = (wid >= 2) ? dA_lds : d5_lds;
        int oh = (wid & 1) * 64;
        int obr = (wid >= 2) ? 128 : 0;

        floatx4 acc[4][4];
#pragma unroll
        for (int i = 0; i < 4; ++i)
#pragma unroll
            for (int j = 0; j < 4; ++j) acc[i][j] = (floatx4){0.f, 0.f, 0.f, 0.f};

#pragma unroll
        for (int ks = 0; ks < 2; ++ks) {
            int kk = ks * 32 + quad * 8;
            short8 a0 = *(const short8*)(fw_lds + (oh + l16)      * 72 + kk);
            short8 a1 = *(const short8*)(fw_lds + (oh + 16 + l16) * 72 + kk);
            short8 a2 = *(const short8*)(fw_lds + (oh + 32 + l16) * 72 + kk);
            short8 a3 = *(const short8*)(fw_lds + (oh + 48 + l16) * 72 + kk);
#pragma unroll
            for (int nt = 0; nt < 4; ++nt) {
                short8 bv = *(const short8*)(dl + (nt * 16 + l16) * 72 + kk);
                acc[0][nt] = __builtin_amdgcn_mfma_f32_16x16x32_bf16(a0, bv, acc[0][nt], 0, 0, 0);
                acc[1][nt] = __builtin_amdgcn_mfma_f32_16x16x32_bf16(a1, bv, acc[1][nt], 0, 0, 0);
                acc[2][nt] = __builtin_amdgcn_mfma_f32_16x16x32_bf16(a2, bv, acc[2][nt], 0, 0, 0);
                acc[3][nt] = __builtin_amdgcn_mfma_f32_16x16x32_bf16(a3, bv, acc[3][nt], 0, 0, 0);
            }
        }
        // D: col=px=l16, row=o=quad*4+reg; out[n][obr+o][y][x] fp32
#pragma unroll
        for (int mt = 0; mt < 4; ++mt) {
            int ob = oh + mt * 16 + quad * 4;
            float b0 = smalls[FB_OFF + ob],     b1 = smalls[FB_OFF + ob + 1];
            float b2 = smalls[FB_OFF + ob + 2], b3 = smalls[FB_OFF + ob + 3];
#pragma unroll
            for (int nt = 0; nt < 4; ++nt) {
                int pxl = nt * 16 + l16;
                int py = pxl >> 3, pxx = pxl & 7;
                size_t base = ((size_t)n * 256 + obr + ob) * HW
                            + (size_t)(y0 + py) * WW + x0 + pxx;
                out[base]          = acc[mt][nt][0] + b0;
                out[base + HW]     = acc[mt][nt][1] + b1;
                out[base + 2 * HW] = acc[mt][nt][2] + b2;
                out[base + 3 * HW] = acc[mt][nt][3] + b3;
            }
        }
    }
}

extern "C" void kernel_launch(void* const* d_in, const int* in_sizes, int n_in,
                              void* d_out, int out_size, void* d_ws, size_t ws_size,
                              hipStream_t stream) {
    float* out = (float*)d_out;                              // fp32 output

    char* ws = (char*)d_ws;
    int*      flags = (int*)ws;                              // 256 B
    uint16_t* cw_bf = (uint16_t*)(ws + 256);                 // 32768 B [o][c]
    uint16_t* fw_bf = (uint16_t*)(ws + 33024);               // 16384 B [o][c]
    float*    smalls = (float*)(ws + 49408);                 // 2048 B
    float*    sums  = (float*)(ws + 65536);                  // 16384 B
    float*    w_dyn = (float*)(ws + 81920);                  // 102400 B
    float*    w_atr = (float*)(ws + 184320);                 // 36864 B
    uint16_t* f     = (uint16_t*)(ws + 221184);              // 18.9 MB [n][px][c] bf16

    k_probe<<<dim3(1), dim3(256), 0, stream>>>(
        (const uint16_t*)d_in[0], (const uint16_t*)d_in[1], flags);
    k_wnorm<<<dim3(1), dim3(256), 0, stream>>>(
        d_in[1], d_in[2], d_in[3], d_in[4], d_in[5], d_in[6], d_in[7], d_in[8],
        d_in[9], d_in[10], d_in[11], d_in[12], d_in[13], d_in[14],
        flags, cw_bf, fw_bf, smalls);
    k_sums<<<dim3(N_S * C_IN), dim3(256), 0, stream>>>(d_in[0], flags, sums);
    k_weights<<<dim3(4), dim3(256), 0, stream>>>(sums, cw_bf, smalls, w_dyn, w_atr);
    k_conv1x1<<<dim3(N_S * 72), dim3(256), 0, stream>>>(d_in[0], flags, cw_bf, smalls, f);
    k_dwfuse<<<dim3(N_S * 144), dim3(256), 0, stream>>>(
        f, w_dyn, w_atr, fw_bf, smalls, out);
}